// Round 4
// baseline (412.148 us; speedup 1.0000x reference)
//
#include <hip/hip_runtime.h>

// Problem: B=4, S=2048, H=16, D=64, E=1024. Inputs fp32, OUTPUT fp32.
// out = proj( attention( cos(x+theta) ) )  with Q==K==V per head.
//
// Round 4: dtype fix — inputs fp32 (proven: bf16 reads NaN'd, fp32 finite),
// d_out fp32 (round-3 err 1.32 == packed-bf16-read-as-fp32 signature).
// Intermediates bf16 for MFMA. ws usage: 16 MiB (attention output only).

#define B_  4
#define S_  2048
#define H_  16
#define D_  64
#define E_  1024
#define SCALE 0.125f  // 1/sqrt(64)

typedef unsigned short u16;
typedef __attribute__((ext_vector_type(8))) short short8;
typedef __attribute__((ext_vector_type(4))) float floatx4;

static __device__ __forceinline__ float bf2f(u16 v) {
    return __uint_as_float(((unsigned)v) << 16);
}
static __device__ __forceinline__ u16 f2bf(float f) {
    unsigned u = __float_as_uint(f);
    return (u16)((u + 0x7FFFu + ((u >> 16) & 1u)) >> 16);
}

// ---------------------------------------------------------------------------
// Flash attention per (bh, q-tile of 64). 256 threads = 4 waves; wave w owns
// q rows [w*16,w*16+16). MFMA 16x16x32 bf16. qkv recomputed from x per tile.
// ---------------------------------------------------------------------------
__global__ __launch_bounds__(256) void attn_kernel(const float* __restrict__ x,
                                                   const float* __restrict__ theta,
                                                   u16* __restrict__ aout) {
    int blk  = blockIdx.x;
    int qt   = blk & 31;
    int bh   = blk >> 5;
    int b    = bh >> 4;
    int h    = bh & 15;
    int tid  = threadIdx.x;
    int wave = tid >> 6;
    int lane = tid & 63;
    int lq   = lane & 15;   // A-frag row / C-frag col
    int lg   = lane >> 4;   // group 0..3
    int r    = tid >> 2;    // staging row 0..63
    int c0   = (tid & 3) << 4;  // staging col base {0,16,32,48}

    __shared__ __align__(16) u16 Qs[64][72];
    __shared__ __align__(16) u16 Kt[64][72];        // K tile [k][d]
    __shared__ __align__(16) u16 Vt[64][72];        // V^T tile [d][k]
    __shared__ __align__(16) u16 Ps[4][16][72];     // per-wave P tile [m][k]

    // theta slice for this thread's 16 columns
    float tv[16];
    {
        const float* tp = theta + h * D_ + c0;
#pragma unroll
        for (int j = 0; j < 16; j += 4) {
            float4 t = *(const float4*)(tp + j);
            tv[j] = t.x; tv[j + 1] = t.y; tv[j + 2] = t.z; tv[j + 3] = t.w;
        }
    }

    const float* xbase = x + (size_t)b * S_ * E_ + h * D_;  // row stride E_
    int s0 = qt * 64;

    // stage Q tile: cos(x + theta)
    {
        const float* p = xbase + (size_t)(s0 + r) * E_ + c0;
        u16 ov[16];
#pragma unroll
        for (int j = 0; j < 16; j += 4) {
            float4 xv = *(const float4*)(p + j);
            ov[j]     = f2bf(__cosf(xv.x + tv[j]));
            ov[j + 1] = f2bf(__cosf(xv.y + tv[j + 1]));
            ov[j + 2] = f2bf(__cosf(xv.z + tv[j + 2]));
            ov[j + 3] = f2bf(__cosf(xv.w + tv[j + 3]));
        }
        *(uint4*)&Qs[r][c0]     = *(uint4*)&ov[0];
        *(uint4*)&Qs[r][c0 + 8] = *(uint4*)&ov[8];
    }
    __syncthreads();

    // Q A-fragments: A[m=lq][k=lg*8+j (+32)]
    short8 aq0 = *(short8*)&Qs[wave * 16 + lq][lg * 8];
    short8 aq1 = *(short8*)&Qs[wave * 16 + lq][32 + lg * 8];

    floatx4 oacc[4] = {{0,0,0,0},{0,0,0,0},{0,0,0,0},{0,0,0,0}};
    float mr[4] = {-1e30f, -1e30f, -1e30f, -1e30f};
    float lr[4] = {0.f, 0.f, 0.f, 0.f};

    for (int kt = 0; kt < S_ / 64; kt++) {
        __syncthreads();   // prev iteration's Kt/Vt/Ps reads complete
        // stage K tile (recompute cos) and V^T via in-LDS transpose (V == K)
        {
            const float* p = xbase + (size_t)(kt * 64 + r) * E_ + c0;
            u16 ov[16];
#pragma unroll
            for (int j = 0; j < 16; j += 4) {
                float4 xv = *(const float4*)(p + j);
                ov[j]     = f2bf(__cosf(xv.x + tv[j]));
                ov[j + 1] = f2bf(__cosf(xv.y + tv[j + 1]));
                ov[j + 2] = f2bf(__cosf(xv.z + tv[j + 2]));
                ov[j + 3] = f2bf(__cosf(xv.w + tv[j + 3]));
            }
            *(uint4*)&Kt[r][c0]     = *(uint4*)&ov[0];
            *(uint4*)&Kt[r][c0 + 8] = *(uint4*)&ov[8];
#pragma unroll
            for (int j = 0; j < 16; j++) Vt[c0 + j][r] = ov[j];
        }
        __syncthreads();

        // S = Q K^T * scale : 4 column tiles of 16 keys
        floatx4 sc[4];
#pragma unroll
        for (int t = 0; t < 4; t++) {
            floatx4 acc = {0, 0, 0, 0};
            short8 b0 = *(short8*)&Kt[t * 16 + lq][lg * 8];   // B[k=d][n=key]
            acc = __builtin_amdgcn_mfma_f32_16x16x32_bf16(aq0, b0, acc, 0, 0, 0);
            short8 b1 = *(short8*)&Kt[t * 16 + lq][32 + lg * 8];
            acc = __builtin_amdgcn_mfma_f32_16x16x32_bf16(aq1, b1, acc, 0, 0, 0);
#pragma unroll
            for (int rr = 0; rr < 4; rr++) acc[rr] *= SCALE;
            sc[t] = acc;
        }

        // online softmax; row lg*4+rr lives in 16 consecutive lanes
#pragma unroll
        for (int rr = 0; rr < 4; rr++) {
            float mx = fmaxf(fmaxf(sc[0][rr], sc[1][rr]), fmaxf(sc[2][rr], sc[3][rr]));
            mx = fmaxf(mx, __shfl_xor(mx, 1, 16));
            mx = fmaxf(mx, __shfl_xor(mx, 2, 16));
            mx = fmaxf(mx, __shfl_xor(mx, 4, 16));
            mx = fmaxf(mx, __shfl_xor(mx, 8, 16));
            float mnew  = fmaxf(mr[rr], mx);
            float alpha = __expf(mr[rr] - mnew);
            mr[rr] = mnew;
            float ps = 0.f;
#pragma unroll
            for (int t = 0; t < 4; t++) {
                float p = __expf(sc[t][rr] - mnew);
                sc[t][rr] = p;
                ps += p;
            }
            ps += __shfl_xor(ps, 1, 16);
            ps += __shfl_xor(ps, 2, 16);
            ps += __shfl_xor(ps, 4, 16);
            ps += __shfl_xor(ps, 8, 16);
            lr[rr] = lr[rr] * alpha + ps;
#pragma unroll
            for (int t = 0; t < 4; t++) oacc[t][rr] *= alpha;
        }

        // write P (C-layout) to per-wave LDS as [m][k] bf16
#pragma unroll
        for (int t = 0; t < 4; t++)
#pragma unroll
            for (int rr = 0; rr < 4; rr++)
                Ps[wave][lg * 4 + rr][t * 16 + lq] = f2bf(sc[t][rr]);

        __syncthreads();

        // O += P[16x64] * V[64x64]
        short8 ap0 = *(short8*)&Ps[wave][lq][lg * 8];
        short8 ap1 = *(short8*)&Ps[wave][lq][32 + lg * 8];
#pragma unroll
        for (int t = 0; t < 4; t++) {
            short8 bv0 = *(short8*)&Vt[t * 16 + lq][lg * 8];   // B[k=key][n=d]
            oacc[t] = __builtin_amdgcn_mfma_f32_16x16x32_bf16(ap0, bv0, oacc[t], 0, 0, 0);
            short8 bv1 = *(short8*)&Vt[t * 16 + lq][32 + lg * 8];
            oacc[t] = __builtin_amdgcn_mfma_f32_16x16x32_bf16(ap1, bv1, oacc[t], 0, 0, 0);
        }
    }

    // epilogue: O /= l, write aout[b][s][h*64+col] (bf16 intermediate)
#pragma unroll
    for (int t = 0; t < 4; t++) {
#pragma unroll
        for (int rr = 0; rr < 4; rr++) {
            float inv = 1.0f / fmaxf(lr[rr], 1e-20f);
            int srow = s0 + wave * 16 + lg * 4 + rr;
            int col  = h * D_ + t * 16 + lq;
            aout[((size_t)(b * S_ + srow)) * E_ + col] = f2bf(oacc[t][rr] * inv);
        }
    }
}

// ---------------------------------------------------------------------------
// out[M=8192][N=1024] = AO * W^T + bias (fp32 out). W fp32 [n][k] = B^T form.
// 64x64 tile per block, 4 waves x (16x64).
// ---------------------------------------------------------------------------
__global__ __launch_bounds__(256) void proj_kernel(const u16* __restrict__ A,
                                                   const float* __restrict__ W,
                                                   const float* __restrict__ bias,
                                                   float* __restrict__ out) {
    int m0   = blockIdx.x * 64;
    int n0   = blockIdx.y * 64;
    int tid  = threadIdx.x;
    int wave = tid >> 6;
    int lane = tid & 63;
    int lq   = lane & 15;
    int lg   = lane >> 4;
    int r    = tid >> 2;
    int c0   = (tid & 3) << 4;

    __shared__ __align__(16) u16 As[64][72];
    __shared__ __align__(16) u16 Bs[64][72];

    floatx4 acc[4] = {{0,0,0,0},{0,0,0,0},{0,0,0,0},{0,0,0,0}};

    for (int kc = 0; kc < E_; kc += 64) {
        __syncthreads();
        const u16* pa = A + (size_t)(m0 + r) * E_ + kc + c0;
        *(uint4*)&As[r][c0]     = *(const uint4*)pa;
        *(uint4*)&As[r][c0 + 8] = *(const uint4*)(pa + 8);
        {
            const float* pw = W + (size_t)(n0 + r) * E_ + kc + c0;
            u16 ov[16];
#pragma unroll
            for (int j = 0; j < 16; j += 4) {
                float4 wv = *(const float4*)(pw + j);
                ov[j]     = f2bf(wv.x);
                ov[j + 1] = f2bf(wv.y);
                ov[j + 2] = f2bf(wv.z);
                ov[j + 3] = f2bf(wv.w);
            }
            *(uint4*)&Bs[r][c0]     = *(uint4*)&ov[0];
            *(uint4*)&Bs[r][c0 + 8] = *(uint4*)&ov[8];
        }
        __syncthreads();

#pragma unroll
        for (int c = 0; c < 2; c++) {
            short8 a = *(short8*)&As[wave * 16 + lq][c * 32 + lg * 8];
#pragma unroll
            for (int t = 0; t < 4; t++) {
                short8 bb = *(short8*)&Bs[t * 16 + lq][c * 32 + lg * 8];
                acc[t] = __builtin_amdgcn_mfma_f32_16x16x32_bf16(a, bb, acc[t], 0, 0, 0);
            }
        }
    }

#pragma unroll
    for (int t = 0; t < 4; t++) {
        int nidx = n0 + t * 16 + lq;
        float bv = bias[nidx];
#pragma unroll
        for (int rr = 0; rr < 4; rr++) {
            int row = m0 + wave * 16 + lg * 4 + rr;
            out[(size_t)row * E_ + nidx] = acc[t][rr] + bv;
        }
    }
}

// ---------------------------------------------------------------------------
extern "C" void kernel_launch(void* const* d_in, const int* in_sizes, int n_in,
                              void* d_out, int out_size, void* d_ws, size_t ws_size,
                              hipStream_t stream) {
    const float* x     = (const float*)d_in[0];
    const float* theta = (const float*)d_in[1];
    const float* w_out = (const float*)d_in[2];
    const float* b_out = (const float*)d_in[3];
    float* out = (float*)d_out;
    u16* aout  = (u16*)d_ws;   // 16 MiB: [B][S][E] bf16 attention output

    attn_kernel<<<(B_ * H_) * (S_ / 64), 256, 0, stream>>>(x, theta, aout);
    dim3 pg(B_ * S_ / 64, E_ / 64);
    proj_kernel<<<pg, 256, 0, stream>>>(aout, w_out, b_out, out);
}